// Round 10
// baseline (2828.280 us; speedup 1.0000x reference)
//
#include <hip/hip_runtime.h>
#include <hip/hip_bf16.h>

#define T_LEN 2048
#define BATCH 32
#define HDIM 256
#define H3 768
#define EMBD 63
#define NSING 1024

typedef _Float16 half2_t __attribute__((ext_vector_type(2)));
typedef _Float16 half4 __attribute__((ext_vector_type(4)));

__device__ __forceinline__ float fdot2u(unsigned int a, unsigned int b, float c) {
  return __builtin_amdgcn_fdot2(__builtin_bit_cast(half2_t, a),
                                __builtin_bit_cast(half2_t, b), c, false);
}

#define DPP_ADD(x, ctrl)                                                      \
  (x) += __builtin_bit_cast(                                                  \
      float, __builtin_amdgcn_update_dpp(                                     \
                 0, __builtin_bit_cast(int, (x)), (ctrl), 0xf, 0xf, true))

// P4[(s*256 + c)*4 + {0,1,2}] = (p_r, p_z, p_n) f16 for one direction.
__global__ __launch_bounds__(256) void precompute_P(
    const float* __restrict__ embed, const float* __restrict__ Wi,
    const float* __restrict__ bi, _Float16* __restrict__ P4) {
  const int s = blockIdx.x;
  const int c = threadIdx.x;
  float ar = bi[c], az = bi[HDIM + c], an = bi[2 * HDIM + c];
  const float* er = embed + s * EMBD;
#pragma unroll
  for (int e = 0; e < EMBD; e++) {
    const float ev = er[e];
    ar += ev * Wi[(e + 1) * H3 + c];
    az += ev * Wi[(e + 1) * H3 + HDIM + c];
    an += ev * Wi[(e + 1) * H3 + 2 * HDIM + c];
  }
  half4 h = {(_Float16)ar, (_Float16)az, (_Float16)an, (_Float16)0.f};
  *(half4*)(P4 + ((size_t)s * HDIM + c) * 4) = h;
}

// Whp[(((d*2+half)*64 + k2)*3 + g)*256 + j] =
//   pack_f16(Wh_d[half*128 + 2*k2][g*256+j], Wh_d[half*128 + 2*k2 + 1][g*256+j])
// (proven correct in round 5: absmax 4.88e-4)
__global__ __launch_bounds__(256) void pack_Wh(
    const float* __restrict__ Wh_f, const float* __restrict__ Wh_b,
    unsigned int* __restrict__ Whp) {
  const int bid = blockIdx.x;  // = d*384 + half*192 + k2*3 + g  (768 blocks)
  const int j = threadIdx.x;
  const int g = bid % 3;
  const int k2 = (bid / 3) & 63;
  const int half = (bid / 192) & 1;
  const int d = bid / 384;
  const float* Wh = d ? Wh_b : Wh_f;
  const int r0 = half * 128 + 2 * k2;
  half2_t hp;
  hp.x = (_Float16)Wh[r0 * H3 + g * 256 + j];
  hp.y = (_Float16)Wh[(r0 + 1) * H3 + g * 256 + j];
  Whp[(size_t)bid * 256 + j] = __builtin_bit_cast(unsigned int, hp);
}

// dot2 scan (round-5 structure) with register-pressure-controlled scheduling.
// 512 threads = 8 waves = 2 waves/SIMD (256 unified regs/wave). Thread
// (j, half) owns K-half of all 3 gate columns: 192 packed-f16 dwords.
//
// Rounds 1-9 post-mortem: the allocator AGPR-homed w[] whenever transient
// arch pressure exceeded 256 -- in r5 the fully-unrolled dot loop hoisted
// all 16 LDS reads to the top (+64 live regs), blowing the budget, and the
// AGPR->VGPR copy per dot2 use cost ~770 cy/step. Fix: sched_barrier(0)
// fences split the dots into 4 regions of {4 x ds_read_b128, 48 x dot2},
// capping live hv at 16 regs. Peak arch pressure ~= 234 <= 256, so w[]
// stays arch-resident and dot2 (VOP3P, VGPR-only srcs) runs copy-free.
__global__ __attribute__((amdgpu_flat_work_group_size(512, 512),
                          amdgpu_waves_per_eu(2, 2))) void gru_scan(
    const float* __restrict__ dur, const int* __restrict__ sid,
    const unsigned int* __restrict__ Whp,
    const float* __restrict__ Wi_f, const float* __restrict__ Wi_b,
    const float* __restrict__ bhn_f, const float* __restrict__ bhn_b,
    const float* __restrict__ Wd,
    const _Float16* __restrict__ P4,  // [dir][s][256][4] f16
    float* __restrict__ pred) {       // [dir][b][t][4]
  const int b = blockIdx.x & 31;
  const int dir = blockIdx.x >> 5;
  const int tid = threadIdx.x;
  const int j = tid & 255;
  const int half = tid >> 8;

  const float* __restrict__ Wi = dir ? Wi_b : Wi_f;
  const _Float16* __restrict__ Pdir = P4 + (size_t)dir * NSING * HDIM * 4;

  __shared__ __align__(16) unsigned int h2buf[2][128];  // packed-f16 h, dbuf
  __shared__ float pbuf[3][256];                        // half=1 partials

  // Load my 192 weight dwords (coalesced: stride-256 rows, j within row).
  unsigned int w[192];
  {
    const unsigned int* wp = Whp + ((size_t)(dir * 2 + half)) * 192 * 256 + j;
#pragma unroll
    for (int i = 0; i < 192; i++) w[i] = wp[i * 256];
  }

  const float wir = Wi[j], wiz = Wi[HDIM + j], win = Wi[2 * HDIM + j];
  const float wd = Wd[dir * HDIM + j];
  const float bh = (dir ? bhn_b : bhn_f)[j];

  if (tid < 128) h2buf[0][tid] = 0u;
  float hprev = 0.f;

  const float* durb = dur + b * T_LEN;
  const int* sidb = sid + b * T_LEN;
  float* predb = pred + ((size_t)(dir * BATCH + b)) * T_LEN * 4;

  // prologue: prefetch step-0 inputs
  const int tt0 = dir ? (T_LEN - 1) : 0;
  half4 pv = *(const half4*)(Pdir + ((size_t)sidb[tt0] * HDIM + j) * 4);
  float d_cur = durb[tt0];
  __syncthreads();

#pragma unroll 1
  for (int t = 0; t < T_LEN; t++) {
    const int cur = t & 1;
    const int tt = dir ? (T_LEN - 1 - t) : t;
    const int tn = (t + 1 < T_LEN) ? (t + 1) : t;
    const int ttn = dir ? (T_LEN - 1 - tn) : tn;

    // next-step prefetch (uniform scalars -> SGPR; pv_nx hides under dots)
    const int s_nx = sidb[ttn];
    const float d_nx = durb[ttn];
    const half4 pv_nx = *(const half4*)(Pdir + ((size_t)s_nx * HDIM + j) * 4);

    // partial dots over my K-half: 4 fenced regions of {4 b128, 48 dot2}
    const uint4* hv4 = (const uint4*)&h2buf[cur][half * 64];
    float ar = 0, az = 0, an = 0, ar2 = 0, az2 = 0, an2 = 0;
#pragma unroll
    for (int blk = 0; blk < 4; blk++) {
#pragma unroll
      for (int kk = blk * 4; kk < blk * 4 + 4; kk++) {
        const uint4 hv = hv4[kk];
        const int bi_ = kk * 12;
        ar = fdot2u(hv.x, w[bi_ + 0], ar);
        az = fdot2u(hv.x, w[bi_ + 1], az);
        an = fdot2u(hv.x, w[bi_ + 2], an);
        ar2 = fdot2u(hv.y, w[bi_ + 3], ar2);
        az2 = fdot2u(hv.y, w[bi_ + 4], az2);
        an2 = fdot2u(hv.y, w[bi_ + 5], an2);
        ar = fdot2u(hv.z, w[bi_ + 6], ar);
        az = fdot2u(hv.z, w[bi_ + 7], az);
        an = fdot2u(hv.z, w[bi_ + 8], an);
        ar2 = fdot2u(hv.w, w[bi_ + 9], ar2);
        az2 = fdot2u(hv.w, w[bi_ + 10], az2);
        an2 = fdot2u(hv.w, w[bi_ + 11], an2);
      }
      __builtin_amdgcn_sched_barrier(0);  // cap live LDS-read regs at 16
    }
    const float sr = ar + ar2, sz = az + az2, sv = an + an2;

    if (half) {
      pbuf[0][j] = sr;
      pbuf[1][j] = sz;
      pbuf[2][j] = sv;
    }
    __syncthreads();  // B1: partials visible

    if (!half) {
      const float ghr = sr + pbuf[0][j];
      const float ghz = sz + pbuf[1][j];
      const float ghn = sv + pbuf[2][j];
      const float r = 1.f / (1.f + __expf(-((float)pv[0] + d_cur * wir + ghr)));
      const float z = 1.f / (1.f + __expf(-((float)pv[1] + d_cur * wiz + ghz)));
      const float nin = (float)pv[2] + d_cur * win + r * (ghn + bh);
      const float n = 1.f - 2.f / (1.f + __expf(2.f * nin));  // tanh, safe
      const float h_new = n + z * (hprev - n);
      hprev = h_new;
      ((unsigned short*)&h2buf[cur ^ 1][0])[j] =
          __builtin_bit_cast(unsigned short, (_Float16)h_new);
      // fused output head: per-wave DPP reduce (waves 0-3 cover all 256 j)
      float pd = h_new * wd;
      DPP_ADD(pd, 0x111);
      DPP_ADD(pd, 0x112);
      DPP_ADD(pd, 0x114);
      DPP_ADD(pd, 0x118);
      DPP_ADD(pd, 0x142);
      DPP_ADD(pd, 0x143);  // lane63 = wave total
      if ((tid & 63) == 63) predb[tt * 4 + (tid >> 6)] = pd;
    }
    __syncthreads();  // B2: h2buf[cur^1] + pbuf reuse safe

    pv = pv_nx;
    d_cur = d_nx;
  }
}

__global__ __launch_bounds__(256) void combine(
    const float* __restrict__ pf, const float* __restrict__ pb,
    const float* __restrict__ bd, float* __restrict__ out) {
  const int i = blockIdx.x * 256 + threadIdx.x;  // i = b*2048 + t
  const float4 a = ((const float4*)pf)[i];
  const float4 c = ((const float4*)pb)[i];
  out[i] = (a.x + a.y + a.z + a.w) + (c.x + c.y + c.z + c.w) + bd[0];
}

extern "C" void kernel_launch(void* const* d_in, const int* in_sizes, int n_in,
                              void* d_out, int out_size, void* d_ws, size_t ws_size,
                              hipStream_t stream) {
  const float* dur = (const float*)d_in[0];
  const int* sid = (const int*)d_in[1];
  const float* embed = (const float*)d_in[2];
  const float* Wi_f = (const float*)d_in[3];
  const float* Wh_f = (const float*)d_in[4];
  const float* bi_f = (const float*)d_in[5];
  const float* bhn_f = (const float*)d_in[6];
  const float* Wi_b = (const float*)d_in[7];
  const float* Wh_b = (const float*)d_in[8];
  const float* bi_b = (const float*)d_in[9];
  const float* bhn_b = (const float*)d_in[10];
  const float* Wd = (const float*)d_in[11];
  const float* bd = (const float*)d_in[12];
  float* out = (float*)d_out;

  // ws (floats): P4 (2*1024*256*4 f16 = 1048576 f) | Whp (196608 dwords) |
  // pred (524288 f). Total ~6.8 MB.
  float* ws = (float*)d_ws;
  _Float16* P4 = (_Float16*)ws;
  unsigned int* Whp = (unsigned int*)(ws + 1048576);
  float* pred = ws + 1048576 + 196608;

  hipLaunchKernelGGL(precompute_P, dim3(NSING), dim3(256), 0, stream,
                     embed, Wi_f, bi_f, P4);
  hipLaunchKernelGGL(precompute_P, dim3(NSING), dim3(256), 0, stream,
                     embed, Wi_b, bi_b, P4 + (size_t)NSING * HDIM * 4);
  hipLaunchKernelGGL(pack_Wh, dim3(768), dim3(256), 0, stream, Wh_f, Wh_b, Whp);
  hipLaunchKernelGGL(gru_scan, dim3(64), dim3(512), 0, stream,
                     dur, sid, Whp, Wi_f, Wi_b, bhn_f, bhn_b, Wd, P4, pred);
  hipLaunchKernelGGL(combine, dim3(256), dim3(256), 0, stream,
                     pred, pred + 262144, bd, out);
}

// Round 11
// 2697.263 us; speedup vs baseline: 1.0486x; 1.0486x over previous
//
#include <hip/hip_runtime.h>
#include <hip/hip_bf16.h>

#define T_LEN 2048
#define BATCH 32
#define HDIM 256
#define H3 768
#define EMBD 63
#define NSING 1024

typedef _Float16 half8 __attribute__((ext_vector_type(8)));
typedef _Float16 half4 __attribute__((ext_vector_type(4)));
typedef float f32x4 __attribute__((ext_vector_type(4)));
typedef unsigned u32x4 __attribute__((ext_vector_type(4)));

#define DPP_ADD(x, ctrl)                                                      \
  (x) += __builtin_bit_cast(                                                  \
      float, __builtin_amdgcn_update_dpp(                                     \
                 0, __builtin_bit_cast(int, (x)), (ctrl), 0xf, 0xf, true))

// P4[(s*256 + c)*4 + {0,1,2}] = (p_r, p_z, p_n) f16 for one direction.
__global__ __launch_bounds__(256) void precompute_P(
    const float* __restrict__ embed, const float* __restrict__ Wi,
    const float* __restrict__ bi, _Float16* __restrict__ P4) {
  const int s = blockIdx.x;
  const int c = threadIdx.x;
  float ar = bi[c], az = bi[HDIM + c], an = bi[2 * HDIM + c];
  const float* er = embed + s * EMBD;
#pragma unroll
  for (int e = 0; e < EMBD; e++) {
    const float ev = er[e];
    ar += ev * Wi[(e + 1) * H3 + c];
    az += ev * Wi[(e + 1) * H3 + HDIM + c];
    an += ev * Wi[(e + 1) * H3 + 2 * HDIM + c];
  }
  half4 h = {(_Float16)ar, (_Float16)az, (_Float16)an, (_Float16)0.f};
  *(half4*)(P4 + ((size_t)s * HDIM + c) * 4) = h;
}

// B-fragment pack, verified LAYOUT_II k-mapping (rounds 6-9 absmax pass).
// bid = ((d*8 + w)*6 + q)*8 + kt ; gate = q>>1, s = q&1 ; nt = gate*16+2w+s
__global__ __launch_bounds__(64) void pack_B(
    const float* __restrict__ Wh_f, const float* __restrict__ Wh_b,
    uint4* __restrict__ Bp) {
  const int bid = blockIdx.x;  // 768 blocks
  const int kt = bid & 7;
  const int idx = bid >> 3;
  const int q = idx % 6;
  const int rest = idx / 6;
  const int w = rest & 7;
  const int d = rest >> 3;
  const int l = threadIdx.x;
  const int g = l >> 4;
  const int gate = q >> 1, s = q & 1;
  const int nt = gate * 16 + 2 * w + s;
  const int j = nt * 16 + (l & 15);
  const float* Wh = d ? Wh_b : Wh_f;
  unsigned int dw[4];
#pragma unroll
  for (int r = 0; r < 4; r++) {
    const int k = kt * 32 + (r >= 2 ? 16 : 0) + g * 4 + (r & 1) * 2;
    _Float16 lo = (_Float16)Wh[k * H3 + j];
    _Float16 hi = (_Float16)Wh[(k + 1) * H3 + j];
    dw[r] = (unsigned int)__builtin_bit_cast(unsigned short, lo) |
            ((unsigned int)__builtin_bit_cast(unsigned short, hi) << 16);
  }
  Bp[(size_t)bid * 64 + l] = make_uint4(dw[0], dw[1], dw[2], dw[3]);
}

// One block per (dir,b): 512 threads = 8 waves = 2 waves/SIMD (256 unified
// regs/wave). Wave w owns cols [32w, 32w+32): 48 B-tiles = 192 dwords.
//
// Rounds 1-10 post-mortem: intrinsic MFMA / dot2 both pay a v_accvgpr_read
// per use of AGPR-homed operands, and the allocator ALWAYS AGPR-homes the
// weight array. r9 proved the one copy-free mechanism: inline-asm MFMA with
// explicit "a" constraints (srcB reads AGPR natively; VALUBusy 7%). This
// kernel = r8's 8-wave shape + r9's asm mechanism: bfr -> "a" (192 AGPR),
// acc -> "v" (24 arch, gate reads free), kt0 C=0 literal kills acc init,
// sched_barrier per kt caps A-load hoisting (arch ~60, total ~252 <= 256).
__global__ __attribute__((amdgpu_flat_work_group_size(512, 512),
                          amdgpu_waves_per_eu(2, 2))) void gru_scan(
    const float* __restrict__ dur, const int* __restrict__ sid,
    const uint4* __restrict__ Bp,
    const float* __restrict__ Wi_f, const float* __restrict__ Wi_b,
    const float* __restrict__ bhn_f, const float* __restrict__ bhn_b,
    const float* __restrict__ Wd, const float* __restrict__ bd,
    const _Float16* __restrict__ P4,  // [dir][s][256][4] f16
    float* __restrict__ out) {        // [B][T] f32, pre-zeroed, atomicAdd
  const int b = blockIdx.x & 31;
  const int dir = blockIdx.x >> 5;
  const int tid = threadIdx.x;
  const int l = tid & 63;
  const int w = tid >> 6;           // wave 0..7
  const int g = (l >> 4) & 3;       // A-fragment lane group
  const int s = l >> 5;             // my N-subtile (0/1) within the wave
  const int c = w * 32 + s * 16 + (l & 15);  // my gate/output column

  __shared__ __align__(16) _Float16 hp[2][HDIM];  // permuted-h, double-buf

  // ---- B fragments: 48 tiles; homes forced to AGPR by the asm "a"
  // constraints at every use (no pin asm -- that forced copies in r8) ----
  u32x4 bfr[48];
  {
    const u32x4* bp = (const u32x4*)(Bp + ((size_t)(dir * 8 + w) * 48) * 64 + l);
#pragma unroll
    for (int i = 0; i < 48; i++) bfr[i] = bp[i * 64];
  }

  const float* __restrict__ Wi = dir ? Wi_b : Wi_f;
  const float wir = Wi[c], wiz = Wi[HDIM + c], win = Wi[2 * HDIM + c];
  const float bh = (dir ? bhn_b : bhn_f)[c];
  const float wd = Wd[dir * HDIM + c];
  const float bdv = bd[0];

  // permuted position of col c in the A-fragment k-order (verified r6-r9):
  const int pos = ((c >> 5) << 5) + (((c & 15) >> 2) << 3) +
                  (((c >> 4) & 1) << 2) + (c & 3);
  char* const hbase = (char*)&hp[0][0];
  unsigned rb = g * 16;         // read base byte (buf 0)
  unsigned wb = 512 + pos * 2;  // write base byte (buf 1)

  if (tid < 128) ((unsigned int*)hbase)[tid] = 0u;  // zero hp[0]
  float hprev = 0.f;

  const float* durb = dur + b * T_LEN;
  const int* sidb = sid + b * T_LEN;
  const _Float16* Pdir = P4 + (size_t)dir * NSING * HDIM * 4;
  float* outb = out + (size_t)b * T_LEN;

  int s_cur = sidb[dir ? (T_LEN - 1) : 0];
  float d_cur = durb[dir ? (T_LEN - 1) : 0];
  __syncthreads();

#pragma unroll 1
  for (int t = 0; t < T_LEN; t++) {
    const int tt = dir ? (T_LEN - 1 - t) : t;
    const int tn = (t + 1 < T_LEN) ? (t + 1) : t;
    const int ttn = dir ? (T_LEN - 1 - tn) : tn;

    // input-gate gather (consumed after MFMAs; latency hides under them)
    const half4 pv = *(const half4*)(Pdir + ((size_t)s_cur * HDIM + c) * 4);
    const int s_nx = sidb[ttn];      // uniform prefetch
    const float d_nx = durb[ttn];

    f32x4 acc[6];
#pragma unroll
    for (int kt = 0; kt < 8; kt++) {
      const half8 a = *(const half8*)(hbase + rb + kt * 64);  // broadcast
      if (kt == 0) {
#pragma unroll
        for (int q = 0; q < 6; q++)
          asm("v_mfma_f32_16x16x32_f16 %0, %1, %2, 0"
              : "=v"(acc[q]) : "v"(a), "a"(bfr[q * 8]));
      } else {
#pragma unroll
        for (int q = 0; q < 6; q++)
          asm("v_mfma_f32_16x16x32_f16 %0, %1, %2, %0"
              : "+v"(acc[q]) : "v"(a), "a"(bfr[q * 8 + kt]));
      }
      __builtin_amdgcn_sched_barrier(0);  // cap live A-regs; keep kt groups
    }
    // hazard fence: >=24 cycles between last MFMA write and VALU acc reads.
    asm volatile("s_nop 7\n\ts_nop 7\n\ts_nop 7"
                 : "+v"(acc[0]), "+v"(acc[1]), "+v"(acc[2]), "+v"(acc[3]),
                   "+v"(acc[4]), "+v"(acc[5]));

    // all acc rows equal (broadcast A) -> reg 0 holds gh for col (tile,l&15)
    const float ghr = s ? acc[1][0] : acc[0][0];
    const float ghz = s ? acc[3][0] : acc[2][0];
    const float ghn = s ? acc[5][0] : acc[4][0];

    const float xr = (float)pv[0] + d_cur * wir + ghr;
    const float xz = (float)pv[1] + d_cur * wiz + ghz;
    const float r = 1.f / (1.f + __expf(-xr));
    const float z = 1.f / (1.f + __expf(-xz));
    const float nin = (float)pv[2] + d_cur * win + r * (ghn + bh);
    const float n = 1.f - 2.f / (1.f + __expf(2.f * nin));  // tanh, safe
    const float h_new = n + z * (hprev - n);
    hprev = h_new;

    if (!(l & 16))  // dedupe: one writer per col
      *(unsigned short*)(hbase + wb) =
          __builtin_bit_cast(unsigned short, (_Float16)h_new);

    // fused output head: zero dup lanes, DPP-reduce, one atomic per wave
    float pd = h_new * wd;
    if (l & 16) pd = 0.f;
    DPP_ADD(pd, 0x111);
    DPP_ADD(pd, 0x112);
    DPP_ADD(pd, 0x114);
    DPP_ADD(pd, 0x118);
    DPP_ADD(pd, 0x142);
    DPP_ADD(pd, 0x143);  // lane63 = wave total over its 32 cols
    if (l == 63) {
      float v = pd;
      if (dir == 0 && w == 0) v += bdv;  // bias added exactly once per elem
      unsafeAtomicAdd(outb + tt, v);
    }

    s_cur = s_nx;
    d_cur = d_nx;
    __syncthreads();  // h writes visible; swap buffers
    rb ^= 512;
    wb ^= 512;
  }
}

extern "C" void kernel_launch(void* const* d_in, const int* in_sizes, int n_in,
                              void* d_out, int out_size, void* d_ws, size_t ws_size,
                              hipStream_t stream) {
  const float* dur = (const float*)d_in[0];
  const int* sid = (const int*)d_in[1];
  const float* embed = (const float*)d_in[2];
  const float* Wi_f = (const float*)d_in[3];
  const float* Wh_f = (const float*)d_in[4];
  const float* bi_f = (const float*)d_in[5];
  const float* bhn_f = (const float*)d_in[6];
  const float* Wi_b = (const float*)d_in[7];
  const float* Wh_b = (const float*)d_in[8];
  const float* bi_b = (const float*)d_in[9];
  const float* bhn_b = (const float*)d_in[10];
  const float* Wd = (const float*)d_in[11];
  const float* bd = (const float*)d_in[12];
  float* out = (float*)d_out;

  // ws: P4 (2 dirs * 1024 * 256 * 4 f16 = 4 MB) | Bp (768*64 uint4 = 768 KB)
  _Float16* P4 = (_Float16*)d_ws;
  uint4* Bp = (uint4*)((char*)d_ws + (size_t)4 * 1024 * 1024);

  hipMemsetAsync(d_out, 0, (size_t)out_size * sizeof(float), stream);
  hipLaunchKernelGGL(precompute_P, dim3(NSING), dim3(256), 0, stream,
                     embed, Wi_f, bi_f, P4);
  hipLaunchKernelGGL(precompute_P, dim3(NSING), dim3(256), 0, stream,
                     embed, Wi_b, bi_b, P4 + (size_t)NSING * HDIM * 4);
  hipLaunchKernelGGL(pack_B, dim3(768), dim3(64), 0, stream, Wh_f, Wh_b, Bp);
  hipLaunchKernelGGL(gru_scan, dim3(64), dim3(512), 0, stream,
                     dur, sid, Bp, Wi_f, Wi_b, bhn_f, bhn_b, Wd, bd, P4, out);
}